// Round 1
// baseline (701.356 us; speedup 1.0000x reference)
//
#include <hip/hip_runtime.h>

#define NDIM 512
#define CDIM 128
#define RDIM (NDIM * NDIM)

typedef __attribute__((ext_vector_type(8))) short bf16x8;
typedef __attribute__((ext_vector_type(8))) unsigned short ushort8;
typedef __attribute__((ext_vector_type(4))) float f32x4;

__device__ __forceinline__ float bf2f(unsigned short u) {
  union { unsigned int i; float f; } v; v.i = ((unsigned int)u) << 16; return v.f;
}
__device__ __forceinline__ unsigned short f2bf(float f) {
  union { float f; unsigned int i; } v; v.f = f;
  unsigned int r = v.i + 0x7fffu + ((v.i >> 16) & 1u);
  return (unsigned short)(r >> 16);
}
__device__ __forceinline__ float sigm(float x) { return 1.0f / (1.0f + __expf(-x)); }

// XOR-swizzled [128][128] ushort tile: element (row, col) -> flat index.
// 16B-unit swizzle keeps ds_read_b128 fragments at <=2-way bank aliasing (free).
__device__ __forceinline__ int sw(int row, int col) {
  return (row << 7) + ((((col >> 3) ^ (row & 7)) << 3) | (col & 7));
}

// ---------------- k0: transpose weights [c][o] f32 -> [o][c] bf16 ----------------
__global__ __launch_bounds__(256) void k0_prep(
    const float* __restrict__ Wga, const float* __restrict__ Wa,
    const float* __restrict__ Wgb, const float* __restrict__ Wb,
    const float* __restrict__ Wgo, const float* __restrict__ Wo,
    unsigned short* __restrict__ wsW) {
  __shared__ unsigned short T[128 * 130];
  const float* src;
  switch (blockIdx.x) {
    case 0: src = Wga; break;
    case 1: src = Wa;  break;
    case 2: src = Wgb; break;
    case 3: src = Wb;  break;
    case 4: src = Wgo; break;
    default: src = Wo; break;
  }
  unsigned short* dst = wsW + blockIdx.x * (CDIM * CDIM);
  const int t = threadIdx.x;
  const int r = t >> 1, hf = t & 1;
  const float* s = src + r * CDIM + hf * 64;
  for (int i = 0; i < 64; i++) T[r * 130 + hf * 64 + i] = f2bf(s[i]);
  __syncthreads();
  unsigned short* d = dst + r * CDIM + hf * 64;
  for (int i = 0; i < 64; i++) d[i] = T[(hf * 64 + i) * 130 + r];
}

// ---------------- k1: LN(z) + 5 projections ----------------
// rows = flattened (i,k); writes a_t/b_t in [o][row] bf16, gate (f32) to d_out.
__global__ __launch_bounds__(256) void k1_proj(
    const float* __restrict__ z, const int* __restrict__ mask,
    const float* __restrict__ g_in, const float* __restrict__ b_in,
    const float* __restrict__ bga, const float* __restrict__ ba,
    const float* __restrict__ bgb, const float* __restrict__ bb,
    const float* __restrict__ bgo, const unsigned short* __restrict__ wsW,
    unsigned short* __restrict__ a_t, unsigned short* __restrict__ b_t,
    float* __restrict__ gate_out) {
  __shared__ unsigned short Xs[CDIM * CDIM];  // zn tile, [row][c] swizzled
  __shared__ unsigned short WT[CDIM * CDIM];  // weight tile / transpose staging
  const int t = threadIdx.x;
  const int lane = t & 63;
  const int w = t >> 6;
  const int l15 = lane & 15;
  const int lq = lane >> 4;
  const int row0 = blockIdx.x * 128;

  // phase 1: load 128 z rows, LayerNorm, write bf16 into Xs
  {
    const int row = t >> 1, hf = t & 1;
    const float4* zp = (const float4*)(z + (size_t)(row0 + row) * CDIM + hf * 64);
    float4 v[16];
    float s = 0.f, s2 = 0.f;
#pragma unroll
    for (int i = 0; i < 16; i++) {
      float4 x = zp[i];
      v[i] = x;
      s += x.x + x.y + x.z + x.w;
      s2 += x.x * x.x + x.y * x.y + x.z * x.z + x.w * x.w;
    }
    s += __shfl_xor(s, 1);
    s2 += __shfl_xor(s2, 1);
    const float mean = s * 0.0078125f;
    const float var = s2 * 0.0078125f - mean * mean;
    const float rs = rsqrtf(var + 1e-5f);
    const float4* gp = (const float4*)(g_in + hf * 64);
    const float4* bp = (const float4*)(b_in + hf * 64);
#pragma unroll
    for (int u = 0; u < 8; u++) {
      float4 x0 = v[2 * u], x1 = v[2 * u + 1];
      float4 g0 = gp[2 * u], g1 = gp[2 * u + 1];
      float4 c0 = bp[2 * u], c1 = bp[2 * u + 1];
      ushort8 pk;
      pk[0] = f2bf((x0.x - mean) * rs * g0.x + c0.x);
      pk[1] = f2bf((x0.y - mean) * rs * g0.y + c0.y);
      pk[2] = f2bf((x0.z - mean) * rs * g0.z + c0.z);
      pk[3] = f2bf((x0.w - mean) * rs * g0.w + c0.w);
      pk[4] = f2bf((x1.x - mean) * rs * g1.x + c1.x);
      pk[5] = f2bf((x1.y - mean) * rs * g1.y + c1.y);
      pk[6] = f2bf((x1.z - mean) * rs * g1.z + c1.z);
      pk[7] = f2bf((x1.w - mean) * rs * g1.w + c1.w);
      const int su = (hf * 8 + u) ^ (row & 7);
      *((ushort8*)&Xs[(row << 7) + (su << 3)]) = pk;
    }
  }

  // mask bits for this lane's D-fragment rows (mask true -> zero a,b)
  unsigned mbits = 0;
#pragma unroll
  for (int ms = 0; ms < 2; ms++)
#pragma unroll
    for (int r = 0; r < 4; r++) {
      const int rl = w * 32 + ms * 16 + (lq << 2) + r;
      if (mask[row0 + rl] != 0) mbits |= 1u << (ms * 4 + r);
    }

  __syncthreads();

  // A fragments held in registers for all 5 GEMMs (X is constant)
  bf16x8 afr[2][4];
#pragma unroll
  for (int ms = 0; ms < 2; ms++) {
    const int m = w * 32 + ms * 16 + l15;
#pragma unroll
    for (int kc = 0; kc < 4; kc++)
      afr[ms][kc] = *((const bf16x8*)&Xs[sw(m, kc * 32 + (lq << 3))]);
  }

  auto stageW = [&](int slot) {
    const unsigned short* Wg = wsW + slot * (CDIM * CDIM);
    const int o = t >> 1, hf = t & 1;
    const uint4* src = (const uint4*)(Wg + o * CDIM + hf * 64);
#pragma unroll
    for (int u = 0; u < 8; u++) {
      const int su = (hf * 8 + u) ^ (o & 7);
      *((uint4*)&WT[(o << 7) + (su << 3)]) = src[u];
    }
  };

  f32x4 accg[2][8], accv[2][8];
  const f32x4 zv = {0.f, 0.f, 0.f, 0.f};

  auto domfma = [&](f32x4 (&acc)[2][8]) {
#pragma unroll
    for (int kc = 0; kc < 4; kc++) {
      const int kk = kc * 32 + (lq << 3);
#pragma unroll
      for (int nf = 0; nf < 8; nf++) {
        bf16x8 bfr = *((const bf16x8*)&WT[sw(nf * 16 + l15, kk)]);
        acc[0][nf] = __builtin_amdgcn_mfma_f32_16x16x32_bf16(afr[0][kc], bfr, acc[0][nf], 0, 0, 0);
        acc[1][nf] = __builtin_amdgcn_mfma_f32_16x16x32_bf16(afr[1][kc], bfr, acc[1][nf], 0, 0, 0);
      }
    }
  };

  // pairs: (Wga,Wa)->a_t, (Wgb,Wb)->b_t
#pragma unroll 1
  for (int pair = 0; pair < 2; pair++) {
#pragma unroll
    for (int i = 0; i < 2; i++)
#pragma unroll
      for (int j = 0; j < 8; j++) { accg[i][j] = zv; accv[i][j] = zv; }
    __syncthreads();
    stageW(pair * 2);
    __syncthreads();
    domfma(accg);
    __syncthreads();
    stageW(pair * 2 + 1);
    __syncthreads();
    domfma(accv);
    const float* bgp = (pair == 0) ? bga : bgb;
    const float* bvp = (pair == 0) ? ba : bb;
    __syncthreads();  // all waves done reading WT as weights
#pragma unroll
    for (int ms = 0; ms < 2; ms++)
#pragma unroll
      for (int nf = 0; nf < 8; nf++) {
        const int n = nf * 16 + l15;
        const float bg = bgp[n], bv = bvp[n];
#pragma unroll
        for (int r = 0; r < 4; r++) {
          const int rl = w * 32 + ms * 16 + (lq << 2) + r;
          float val = sigm(accg[ms][nf][r] + bg) * (accv[ms][nf][r] + bv);
          if ((mbits >> (ms * 4 + r)) & 1u) val = 0.f;
          WT[sw(n, rl)] = f2bf(val);  // WT reused as transpose buffer [o][row]
        }
      }
    __syncthreads();
    unsigned short* dst = (pair == 0) ? a_t : b_t;
    {
      const int o = t >> 1, hf = t & 1;
#pragma unroll
      for (int u = 0; u < 8; u++) {
        const int ru = hf * 8 + u;
        const int su = ru ^ (o & 7);
        uint4 val = *((const uint4*)&WT[(o << 7) + (su << 3)]);
        *((uint4*)&dst[(size_t)o * RDIM + row0 + ru * 8]) = val;
      }
    }
  }

  // gate GEMM (Wgo): D-layout already matches [row][o] -> direct f32 store
#pragma unroll
  for (int i = 0; i < 2; i++)
#pragma unroll
    for (int j = 0; j < 8; j++) accg[i][j] = zv;
  __syncthreads();
  stageW(4);
  __syncthreads();
  domfma(accg);
#pragma unroll
  for (int ms = 0; ms < 2; ms++)
#pragma unroll
    for (int nf = 0; nf < 8; nf++) {
      const int n = nf * 16 + l15;
      const float bg = bgo[n];
#pragma unroll
      for (int r = 0; r < 4; r++) {
        const int rl = w * 32 + ms * 16 + (lq << 2) + r;
        gate_out[(size_t)(row0 + rl) * CDIM + n] = sigm(accg[ms][nf][r] + bg);
      }
    }
}

// ---------------- k2: einsum = per-channel NT GEMM K_o = A_o * B_o^T ----------------
__global__ __launch_bounds__(256) void k2_einsum(
    const unsigned short* __restrict__ a_t, const unsigned short* __restrict__ b_t,
    unsigned short* __restrict__ k_t) {
  __shared__ unsigned short As[128 * 72];
  __shared__ unsigned short Bs[128 * 72];
  const int t = threadIdx.x;
  const int lane = t & 63;
  const int w = t >> 6;
  const int l15 = lane & 15, lq = lane >> 4;
  const int o = blockIdx.x >> 4;
  const int tile = blockIdx.x & 15;
  const int i0 = (tile >> 2) * 128, j0 = (tile & 3) * 128;
  const size_t base = (size_t)o * RDIM;

  f32x4 acc[2][8];
  const f32x4 zv = {0.f, 0.f, 0.f, 0.f};
#pragma unroll
  for (int i = 0; i < 2; i++)
#pragma unroll
    for (int j = 0; j < 8; j++) acc[i][j] = zv;

  const int r = t & 127;
  const int isB = t >> 7;
  const unsigned short* srcp = (isB ? b_t : a_t) + base + (size_t)((isB ? j0 : i0) + r) * NDIM;
  unsigned short* dstp = isB ? &Bs[r * 72] : &As[r * 72];

  for (int k0 = 0; k0 < NDIM; k0 += 64) {
    __syncthreads();
    const uint4* s4 = (const uint4*)(srcp + k0);
#pragma unroll
    for (int u = 0; u < 8; u++) *((uint4*)&dstp[u * 8]) = s4[u];
    __syncthreads();
#pragma unroll
    for (int kc = 0; kc < 2; kc++) {
      const int kk = kc * 32 + (lq << 3);
      bf16x8 a0 = *((const bf16x8*)&As[(w * 32 + l15) * 72 + kk]);
      bf16x8 a1 = *((const bf16x8*)&As[(w * 32 + 16 + l15) * 72 + kk]);
#pragma unroll
      for (int nf = 0; nf < 8; nf++) {
        bf16x8 bfr = *((const bf16x8*)&Bs[(nf * 16 + l15) * 72 + kk]);
        acc[0][nf] = __builtin_amdgcn_mfma_f32_16x16x32_bf16(a0, bfr, acc[0][nf], 0, 0, 0);
        acc[1][nf] = __builtin_amdgcn_mfma_f32_16x16x32_bf16(a1, bfr, acc[1][nf], 0, 0, 0);
      }
    }
  }
#pragma unroll
  for (int ms = 0; ms < 2; ms++)
#pragma unroll
    for (int nf = 0; nf < 8; nf++)
#pragma unroll
      for (int r2 = 0; r2 < 4; r2++) {
        const int mi = i0 + w * 32 + ms * 16 + (lq << 2) + r2;
        const int nj = j0 + nf * 16 + l15;
        k_t[base + (size_t)mi * NDIM + nj] = f2bf(acc[ms][nf][r2]);
      }
}

// ---------------- k3: LN(k) @ Wo + bo, times gate (in-place on d_out) ----------------
__global__ __launch_bounds__(256) void k3_final(
    const unsigned short* __restrict__ k_t, const unsigned short* __restrict__ wsW,
    const float* __restrict__ g_o, const float* __restrict__ b_o,
    const float* __restrict__ bo, float* __restrict__ out) {
  __shared__ unsigned short Ks[CDIM * CDIM];  // [o][row] swizzled; later reused for Wo
  __shared__ unsigned short XN[CDIM * CDIM];  // normalized k, [row][o] swizzled
  const int t = threadIdx.x;
  const int lane = t & 63;
  const int w = t >> 6;
  const int l15 = lane & 15, lq = lane >> 4;
  const int row0 = blockIdx.x * 128;

  // stage k tile (transposed source layout [o][row])
  {
    const int o = t >> 1, hf = t & 1;
    const uint4* src = (const uint4*)(k_t + (size_t)o * RDIM + row0 + hf * 64);
#pragma unroll
    for (int u = 0; u < 8; u++) {
      const int ru = hf * 8 + u;
      const int su = ru ^ (o & 7);
      *((uint4*)&Ks[(o << 7) + (su << 3)]) = src[u];
    }
  }
  __syncthreads();
  // per-row (over channels) LayerNorm, build A tile
  {
    const int row = t >> 1, hf = t & 1;
    float x[64];
    float s = 0.f, s2 = 0.f;
#pragma unroll
    for (int i = 0; i < 64; i++) {
      x[i] = bf2f(Ks[sw(hf * 64 + i, row)]);
      s += x[i];
      s2 += x[i] * x[i];
    }
    s += __shfl_xor(s, 1);
    s2 += __shfl_xor(s2, 1);
    const float mean = s * 0.0078125f;
    const float var = s2 * 0.0078125f - mean * mean;
    const float rs = rsqrtf(var + 1e-5f);
#pragma unroll
    for (int i = 0; i < 64; i++) {
      const int o = hf * 64 + i;
      XN[sw(row, o)] = f2bf((x[i] - mean) * rs * g_o[o] + b_o[o]);
    }
  }
  __syncthreads();
  // stage Wo^T over Ks (Ks fully consumed)
  {
    const unsigned short* Wg = wsW + 5 * (CDIM * CDIM);
    const int o = t >> 1, hf = t & 1;
    const uint4* src = (const uint4*)(Wg + o * CDIM + hf * 64);
#pragma unroll
    for (int u = 0; u < 8; u++) {
      const int su = (hf * 8 + u) ^ (o & 7);
      *((uint4*)&Ks[(o << 7) + (su << 3)]) = src[u];
    }
  }
  __syncthreads();

  f32x4 acc[2][8];
  const f32x4 zv = {0.f, 0.f, 0.f, 0.f};
#pragma unroll
  for (int i = 0; i < 2; i++)
#pragma unroll
    for (int j = 0; j < 8; j++) acc[i][j] = zv;

  bf16x8 afr[2][4];
#pragma unroll
  for (int ms = 0; ms < 2; ms++) {
    const int m = w * 32 + ms * 16 + l15;
#pragma unroll
    for (int kc = 0; kc < 4; kc++)
      afr[ms][kc] = *((const bf16x8*)&XN[sw(m, kc * 32 + (lq << 3))]);
  }
#pragma unroll
  for (int kc = 0; kc < 4; kc++) {
    const int kk = kc * 32 + (lq << 3);
#pragma unroll
    for (int nf = 0; nf < 8; nf++) {
      bf16x8 bfr = *((const bf16x8*)&Ks[sw(nf * 16 + l15, kk)]);
      acc[0][nf] = __builtin_amdgcn_mfma_f32_16x16x32_bf16(afr[0][kc], bfr, acc[0][nf], 0, 0, 0);
      acc[1][nf] = __builtin_amdgcn_mfma_f32_16x16x32_bf16(afr[1][kc], bfr, acc[1][nf], 0, 0, 0);
    }
  }
#pragma unroll
  for (int ms = 0; ms < 2; ms++)
#pragma unroll
    for (int nf = 0; nf < 8; nf++) {
      const int n = nf * 16 + l15;
      const float bn = bo[n];
#pragma unroll
      for (int r = 0; r < 4; r++) {
        const int rl = w * 32 + ms * 16 + (lq << 2) + r;
        const size_t idx = (size_t)(row0 + rl) * CDIM + n;
        out[idx] = out[idx] * (acc[ms][nf][r] + bn);  // gate was stored here by k1
      }
    }
}

extern "C" void kernel_launch(void* const* d_in, const int* in_sizes, int n_in,
                              void* d_out, int out_size, void* d_ws, size_t ws_size,
                              hipStream_t stream) {
  const float* z    = (const float*)d_in[0];
  const int*   mask = (const int*)d_in[1];
  const float* g_in = (const float*)d_in[2];
  const float* b_in = (const float*)d_in[3];
  const float* Wa   = (const float*)d_in[4];
  const float* ba   = (const float*)d_in[5];
  const float* Wga  = (const float*)d_in[6];
  const float* bga  = (const float*)d_in[7];
  const float* Wb   = (const float*)d_in[8];
  const float* bb   = (const float*)d_in[9];
  const float* Wgb  = (const float*)d_in[10];
  const float* bgb  = (const float*)d_in[11];
  const float* g_o  = (const float*)d_in[12];
  const float* b_o  = (const float*)d_in[13];
  const float* Wgo  = (const float*)d_in[14];
  const float* bgo  = (const float*)d_in[15];
  const float* Wo   = (const float*)d_in[16];
  const float* bo   = (const float*)d_in[17];
  float* out = (float*)d_out;

  unsigned short* wsW = (unsigned short*)d_ws;           // 6 * 128*128 bf16 weights
  unsigned short* a_t = wsW + 6 * (CDIM * CDIM);         // [C][N*N] bf16
  unsigned short* b_t = a_t + (size_t)CDIM * RDIM;
  unsigned short* k_t = b_t + (size_t)CDIM * RDIM;

  k0_prep<<<6, 256, 0, stream>>>(Wga, Wa, Wgb, Wb, Wgo, Wo, wsW);
  k1_proj<<<RDIM / 128, 256, 0, stream>>>(z, mask, g_in, b_in, bga, ba, bgb, bb,
                                          bgo, wsW, a_t, b_t, out);
  k2_einsum<<<CDIM * 16, 256, 0, stream>>>(a_t, b_t, k_t);
  k3_final<<<RDIM / 128, 256, 0, stream>>>(k_t, wsW, g_o, b_o, bo, out);
}

// Round 3
// 674.145 us; speedup vs baseline: 1.0404x; 1.0404x over previous
//
#include <hip/hip_runtime.h>

#define NDIM 512
#define CDIM 128
#define RDIM (NDIM * NDIM)

typedef __attribute__((ext_vector_type(8))) short bf16x8;
typedef __attribute__((ext_vector_type(8))) unsigned short ushort8;
typedef __attribute__((ext_vector_type(4))) float f32x4;

__device__ __forceinline__ float bf2f(unsigned short u) {
  union { unsigned int i; float f; } v; v.i = ((unsigned int)u) << 16; return v.f;
}
__device__ __forceinline__ unsigned short f2bf(float f) {
  union { float f; unsigned int i; } v; v.f = f;
  unsigned int r = v.i + 0x7fffu + ((v.i >> 16) & 1u);
  return (unsigned short)(r >> 16);
}
__device__ __forceinline__ float sigm(float x) { return 1.0f / (1.0f + __expf(-x)); }

// XOR-swizzled [128][128] ushort tile (stride 128, 16B-granule swizzle).
__device__ __forceinline__ int sw(int row, int col) {
  return (row << 7) + ((((col >> 3) ^ (row & 7)) << 3) | (col & 7));
}

// ---------------- k0: weights -> (a) [o][c] bf16 tiles (for k3), (b) MFMA B-frag blob (k1)
// frag(kc,nf), lane L, j: value W[kc*32+(L>>4)*8+j][nf*16+(L&15)]
__global__ __launch_bounds__(256) void k0_prep(
    const float* __restrict__ Wga, const float* __restrict__ Wa,
    const float* __restrict__ Wgb, const float* __restrict__ Wb,
    const float* __restrict__ Wgo, const float* __restrict__ Wo,
    unsigned short* __restrict__ wsT, unsigned short* __restrict__ wsF) {
  __shared__ unsigned short T[128 * 130];
  const float* src;
  switch (blockIdx.x) {
    case 0: src = Wga; break;
    case 1: src = Wa;  break;
    case 2: src = Wgb; break;
    case 3: src = Wb;  break;
    case 4: src = Wgo; break;
    default: src = Wo; break;
  }
  const int t = threadIdx.x;
  // (a) round-1 tile transpose -> wsT
  unsigned short* dstT = wsT + blockIdx.x * (CDIM * CDIM);
  const int r = t >> 1, hf = t & 1;
  const float* s = src + r * CDIM + hf * 64;
  for (int i = 0; i < 64; i++) T[r * 130 + hf * 64 + i] = f2bf(s[i]);
  __syncthreads();
  unsigned short* d = dstT + r * CDIM + hf * 64;
  for (int i = 0; i < 64; i++) d[i] = T[(hf * 64 + i) * 130 + r];
  // (b) fragment-ordered blob -> wsF
  unsigned short* dstF = wsF + blockIdx.x * 16384;
  for (int gid = t; gid < 2048; gid += 256) {
    const int fragid = gid >> 6, lane = gid & 63;
    const int kc = fragid >> 3, nf = fragid & 7;
    const int o = nf * 16 + (lane & 15);
    const int c0 = kc * 32 + (lane >> 4) * 8;
#pragma unroll
    for (int j = 0; j < 8; j++) dstF[gid * 8 + j] = f2bf(src[(c0 + j) * CDIM + o]);
  }
}

__device__ __forceinline__ bf16x8 ldfrag(const unsigned short* wf, int slot, int kc,
                                         int nf, int lane) {
  return *((const bf16x8*)(wf + (((slot * 32 + kc * 8 + nf) * 64 + lane) << 3)));
}

// ---------------- k1: LN(z) + 5 projections (weights from global frags) -----------
__global__ __launch_bounds__(256, 3) void k1_proj(
    const float* __restrict__ z, const int* __restrict__ mask,
    const float* __restrict__ g_in, const float* __restrict__ b_in,
    const float* __restrict__ bga, const float* __restrict__ ba,
    const float* __restrict__ bgb, const float* __restrict__ bb,
    const float* __restrict__ bgo, const unsigned short* __restrict__ wf,
    unsigned short* __restrict__ a_t, unsigned short* __restrict__ b_t,
    float* __restrict__ gate_out) {
  __shared__ unsigned short Xs[CDIM * CDIM];  // 32 KB: zn tile, then transpose buf
  const int t = threadIdx.x;
  const int lane = t & 63;
  const int w = t >> 6;
  const int l15 = lane & 15, lq = lane >> 4;
  const int row0 = blockIdx.x * 128;

  // ---- LN: pass 1 (stats), pass 2 (normalize -> Xs bf16) ----
  {
    const int row = t >> 1, hf = t & 1;
    const float4* zp = (const float4*)(z + (size_t)(row0 + row) * CDIM + hf * 64);
    float s = 0.f, s2 = 0.f;
#pragma unroll
    for (int i = 0; i < 16; i++) {
      float4 x = zp[i];
      s += x.x + x.y + x.z + x.w;
      s2 += x.x * x.x + x.y * x.y + x.z * x.z + x.w * x.w;
    }
    s += __shfl_xor(s, 1);
    s2 += __shfl_xor(s2, 1);
    const float mean = s * 0.0078125f;
    const float var = s2 * 0.0078125f - mean * mean;
    const float rs = rsqrtf(var + 1e-5f);
    const float4* gp = (const float4*)(g_in + hf * 64);
    const float4* bp = (const float4*)(b_in + hf * 64);
#pragma unroll 4
    for (int u = 0; u < 8; u++) {
      float4 x0 = zp[2 * u], x1 = zp[2 * u + 1];
      float4 g0 = gp[2 * u], g1 = gp[2 * u + 1];
      float4 c0 = bp[2 * u], c1 = bp[2 * u + 1];
      ushort8 pk;
      pk[0] = f2bf((x0.x - mean) * rs * g0.x + c0.x);
      pk[1] = f2bf((x0.y - mean) * rs * g0.y + c0.y);
      pk[2] = f2bf((x0.z - mean) * rs * g0.z + c0.z);
      pk[3] = f2bf((x0.w - mean) * rs * g0.w + c0.w);
      pk[4] = f2bf((x1.x - mean) * rs * g1.x + c1.x);
      pk[5] = f2bf((x1.y - mean) * rs * g1.y + c1.y);
      pk[6] = f2bf((x1.z - mean) * rs * g1.z + c1.z);
      pk[7] = f2bf((x1.w - mean) * rs * g1.w + c1.w);
      const int su = (hf * 8 + u) ^ (row & 7);
      *((ushort8*)&Xs[(row << 7) + (su << 3)]) = pk;
    }
  }

  unsigned mbits = 0;
#pragma unroll
  for (int ms = 0; ms < 2; ms++)
#pragma unroll
    for (int r = 0; r < 4; r++) {
      const int rl = w * 32 + ms * 16 + (lq << 2) + r;
      if (mask[row0 + rl] != 0) mbits |= 1u << (ms * 4 + r);
    }

  __syncthreads();

  bf16x8 afr[2][4];
#pragma unroll
  for (int ms = 0; ms < 2; ms++) {
    const int m = w * 32 + ms * 16 + l15;
#pragma unroll
    for (int kc = 0; kc < 4; kc++)
      afr[ms][kc] = *((const bf16x8*)&Xs[sw(m, kc * 32 + (lq << 3))]);
  }
  __syncthreads();  // Xs now reusable as transpose buffer

  const f32x4 zv = {0.f, 0.f, 0.f, 0.f};

  // ---- pairs: (Wga,Wa)->a_t, (Wgb,Wb)->b_t ----
#pragma unroll 1
  for (int pair = 0; pair < 2; pair++) {
    const int sg = pair * 2, sv = pair * 2 + 1;
    const float* bgp = (pair == 0) ? bga : bgb;
    const float* bvp = (pair == 0) ? ba : bb;
#pragma unroll 1
    for (int half = 0; half < 2; half++) {
      f32x4 accg[2][4], accv[2][4];
#pragma unroll
      for (int i = 0; i < 2; i++)
#pragma unroll
        for (int j = 0; j < 4; j++) { accg[i][j] = zv; accv[i][j] = zv; }
#pragma unroll
      for (int kc = 0; kc < 4; kc++) {
#pragma unroll
        for (int nfh = 0; nfh < 4; nfh++) {
          const int fi = half * 4 + nfh;
          bf16x8 bg = ldfrag(wf, sg, kc, fi, lane);
          bf16x8 bv = ldfrag(wf, sv, kc, fi, lane);
          accg[0][nfh] = __builtin_amdgcn_mfma_f32_16x16x32_bf16(afr[0][kc], bg, accg[0][nfh], 0, 0, 0);
          accg[1][nfh] = __builtin_amdgcn_mfma_f32_16x16x32_bf16(afr[1][kc], bg, accg[1][nfh], 0, 0, 0);
          accv[0][nfh] = __builtin_amdgcn_mfma_f32_16x16x32_bf16(afr[0][kc], bv, accv[0][nfh], 0, 0, 0);
          accv[1][nfh] = __builtin_amdgcn_mfma_f32_16x16x32_bf16(afr[1][kc], bv, accv[1][nfh], 0, 0, 0);
        }
      }
#pragma unroll
      for (int ms = 0; ms < 2; ms++)
#pragma unroll
        for (int nfh = 0; nfh < 4; nfh++) {
          const int n = half * 64 + nfh * 16 + l15;
          const float bg = bgp[n], bv = bvp[n];
#pragma unroll
          for (int r = 0; r < 4; r++) {
            const int rl = w * 32 + ms * 16 + (lq << 2) + r;
            float val = sigm(accg[ms][nfh][r] + bg) * (accv[ms][nfh][r] + bv);
            if ((mbits >> (ms * 4 + r)) & 1u) val = 0.f;
            Xs[sw(n, rl)] = f2bf(val);  // transpose buffer [o][row]
          }
        }
    }
    __syncthreads();
    unsigned short* dst = (pair == 0) ? a_t : b_t;
    {
      const int o = t >> 1, hf = t & 1;
#pragma unroll
      for (int u = 0; u < 8; u++) {
        const int ru = hf * 8 + u;
        const int su = ru ^ (o & 7);
        uint4 val = *((const uint4*)&Xs[(o << 7) + (su << 3)]);
        *((uint4*)&dst[(size_t)o * RDIM + row0 + ru * 8]) = val;
      }
    }
    __syncthreads();
  }

  // ---- gate GEMM (Wgo): direct f32 store, D-layout matches [row][o] ----
#pragma unroll 1
  for (int half = 0; half < 2; half++) {
    f32x4 accg[2][4];
#pragma unroll
    for (int i = 0; i < 2; i++)
#pragma unroll
      for (int j = 0; j < 4; j++) accg[i][j] = zv;
#pragma unroll
    for (int kc = 0; kc < 4; kc++) {
#pragma unroll
      for (int nfh = 0; nfh < 4; nfh++) {
        bf16x8 bg = ldfrag(wf, 4, kc, half * 4 + nfh, lane);
        accg[0][nfh] = __builtin_amdgcn_mfma_f32_16x16x32_bf16(afr[0][kc], bg, accg[0][nfh], 0, 0, 0);
        accg[1][nfh] = __builtin_amdgcn_mfma_f32_16x16x32_bf16(afr[1][kc], bg, accg[1][nfh], 0, 0, 0);
      }
    }
#pragma unroll
    for (int ms = 0; ms < 2; ms++)
#pragma unroll
      for (int nfh = 0; nfh < 4; nfh++) {
        const int n = half * 64 + nfh * 16 + l15;
        const float bg = bgo[n];
#pragma unroll
        for (int r = 0; r < 4; r++) {
          const int rl = w * 32 + ms * 16 + (lq << 2) + r;
          gate_out[(size_t)(row0 + rl) * CDIM + n] = sigm(accg[ms][nfh][r] + bg);
        }
      }
  }
}

// ---------------- k2: per-channel NT GEMM (round-1 verbatim) ----------------
__global__ __launch_bounds__(256) void k2_einsum(
    const unsigned short* __restrict__ a_t, const unsigned short* __restrict__ b_t,
    unsigned short* __restrict__ k_t) {
  __shared__ unsigned short As[128 * 72];
  __shared__ unsigned short Bs[128 * 72];
  const int t = threadIdx.x;
  const int lane = t & 63;
  const int w = t >> 6;
  const int l15 = lane & 15, lq = lane >> 4;
  const int o = blockIdx.x >> 4;
  const int tile = blockIdx.x & 15;
  const int i0 = (tile >> 2) * 128, j0 = (tile & 3) * 128;
  const size_t base = (size_t)o * RDIM;

  f32x4 acc[2][8];
  const f32x4 zv = {0.f, 0.f, 0.f, 0.f};
#pragma unroll
  for (int i = 0; i < 2; i++)
#pragma unroll
    for (int j = 0; j < 8; j++) acc[i][j] = zv;

  const int r = t & 127;
  const int isB = t >> 7;
  const unsigned short* srcp = (isB ? b_t : a_t) + base + (size_t)((isB ? j0 : i0) + r) * NDIM;
  unsigned short* dstp = isB ? &Bs[r * 72] : &As[r * 72];

  for (int k0 = 0; k0 < NDIM; k0 += 64) {
    __syncthreads();
    const uint4* s4 = (const uint4*)(srcp + k0);
#pragma unroll
    for (int u = 0; u < 8; u++) *((uint4*)&dstp[u * 8]) = s4[u];
    __syncthreads();
#pragma unroll
    for (int kc = 0; kc < 2; kc++) {
      const int kk = kc * 32 + (lq << 3);
      bf16x8 a0 = *((const bf16x8*)&As[(w * 32 + l15) * 72 + kk]);
      bf16x8 a1 = *((const bf16x8*)&As[(w * 32 + 16 + l15) * 72 + kk]);
#pragma unroll
      for (int nf = 0; nf < 8; nf++) {
        bf16x8 bfr = *((const bf16x8*)&Bs[(nf * 16 + l15) * 72 + kk]);
        acc[0][nf] = __builtin_amdgcn_mfma_f32_16x16x32_bf16(a0, bfr, acc[0][nf], 0, 0, 0);
        acc[1][nf] = __builtin_amdgcn_mfma_f32_16x16x32_bf16(a1, bfr, acc[1][nf], 0, 0, 0);
      }
    }
  }
#pragma unroll
  for (int ms = 0; ms < 2; ms++)
#pragma unroll
    for (int nf = 0; nf < 8; nf++)
#pragma unroll
      for (int r2 = 0; r2 < 4; r2++) {
        const int mi = i0 + w * 32 + ms * 16 + (lq << 2) + r2;
        const int nj = j0 + nf * 16 + l15;
        k_t[base + (size_t)mi * NDIM + nj] = f2bf(acc[ms][nf][r2]);
      }
}

// ---------------- k3: LN(k) @ Wo + bo, times gate (round-1 verbatim) ----------------
__global__ __launch_bounds__(256) void k3_final(
    const unsigned short* __restrict__ k_t, const unsigned short* __restrict__ wsW,
    const float* __restrict__ g_o, const float* __restrict__ b_o,
    const float* __restrict__ bo, float* __restrict__ out) {
  __shared__ unsigned short Ks[CDIM * CDIM];  // [o][row] swizzled; later reused for Wo
  __shared__ unsigned short XN[CDIM * CDIM];  // normalized k, [row][o] swizzled
  const int t = threadIdx.x;
  const int lane = t & 63;
  const int w = t >> 6;
  const int l15 = lane & 15, lq = lane >> 4;
  const int row0 = blockIdx.x * 128;

  // stage k tile (transposed source layout [o][row])
  {
    const int o = t >> 1, hf = t & 1;
    const uint4* src = (const uint4*)(k_t + (size_t)o * RDIM + row0 + hf * 64);
#pragma unroll
    for (int u = 0; u < 8; u++) {
      const int ru = hf * 8 + u;
      const int su = ru ^ (o & 7);
      *((uint4*)&Ks[(o << 7) + (su << 3)]) = src[u];
    }
  }
  __syncthreads();
  // per-row (over channels) LayerNorm, build A tile
  {
    const int row = t >> 1, hf = t & 1;
    float x[64];
    float s = 0.f, s2 = 0.f;
#pragma unroll
    for (int i = 0; i < 64; i++) {
      x[i] = bf2f(Ks[sw(hf * 64 + i, row)]);
      s += x[i];
      s2 += x[i] * x[i];
    }
    s += __shfl_xor(s, 1);
    s2 += __shfl_xor(s2, 1);
    const float mean = s * 0.0078125f;
    const float var = s2 * 0.0078125f - mean * mean;
    const float rs = rsqrtf(var + 1e-5f);
#pragma unroll
    for (int i = 0; i < 64; i++) {
      const int o = hf * 64 + i;
      XN[sw(row, o)] = f2bf((x[i] - mean) * rs * g_o[o] + b_o[o]);
    }
  }
  __syncthreads();
  // stage Wo^T over Ks (Ks fully consumed)
  {
    const unsigned short* Wg = wsW + 5 * (CDIM * CDIM);
    const int o = t >> 1, hf = t & 1;
    const uint4* src = (const uint4*)(Wg + o * CDIM + hf * 64);
#pragma unroll
    for (int u = 0; u < 8; u++) {
      const int su = (hf * 8 + u) ^ (o & 7);
      *((uint4*)&Ks[(o << 7) + (su << 3)]) = src[u];
    }
  }
  __syncthreads();

  f32x4 acc[2][8];
  const f32x4 zv = {0.f, 0.f, 0.f, 0.f};
#pragma unroll
  for (int i = 0; i < 2; i++)
#pragma unroll
    for (int j = 0; j < 8; j++) acc[i][j] = zv;

  bf16x8 afr[2][4];
#pragma unroll
  for (int ms = 0; ms < 2; ms++) {
    const int m = w * 32 + ms * 16 + l15;
#pragma unroll
    for (int kc = 0; kc < 4; kc++)
      afr[ms][kc] = *((const bf16x8*)&XN[sw(m, kc * 32 + (lq << 3))]);
  }
#pragma unroll
  for (int kc = 0; kc < 4; kc++) {
    const int kk = kc * 32 + (lq << 3);
#pragma unroll
    for (int nf = 0; nf < 8; nf++) {
      bf16x8 bfr = *((const bf16x8*)&Ks[sw(nf * 16 + l15, kk)]);
      acc[0][nf] = __builtin_amdgcn_mfma_f32_16x16x32_bf16(afr[0][kc], bfr, acc[0][nf], 0, 0, 0);
      acc[1][nf] = __builtin_amdgcn_mfma_f32_16x16x32_bf16(afr[1][kc], bfr, acc[1][nf], 0, 0, 0);
    }
  }
#pragma unroll
  for (int ms = 0; ms < 2; ms++)
#pragma unroll
    for (int nf = 0; nf < 8; nf++) {
      const int n = nf * 16 + l15;
      const float bn = bo[n];
#pragma unroll
      for (int r = 0; r < 4; r++) {
        const int rl = w * 32 + ms * 16 + (lq << 2) + r;
        const size_t idx = (size_t)(row0 + rl) * CDIM + n;
        out[idx] = out[idx] * (acc[ms][nf][r] + bn);
      }
    }
}

extern "C" void kernel_launch(void* const* d_in, const int* in_sizes, int n_in,
                              void* d_out, int out_size, void* d_ws, size_t ws_size,
                              hipStream_t stream) {
  const float* z    = (const float*)d_in[0];
  const int*   mask = (const int*)d_in[1];
  const float* g_in = (const float*)d_in[2];
  const float* b_in = (const float*)d_in[3];
  const float* Wa   = (const float*)d_in[4];
  const float* ba   = (const float*)d_in[5];
  const float* Wga  = (const float*)d_in[6];
  const float* bga  = (const float*)d_in[7];
  const float* Wb   = (const float*)d_in[8];
  const float* bb   = (const float*)d_in[9];
  const float* Wgb  = (const float*)d_in[10];
  const float* bgb  = (const float*)d_in[11];
  const float* g_o  = (const float*)d_in[12];
  const float* b_o  = (const float*)d_in[13];
  const float* Wgo  = (const float*)d_in[14];
  const float* bgo  = (const float*)d_in[15];
  const float* Wo   = (const float*)d_in[16];
  const float* bo   = (const float*)d_in[17];
  float* out = (float*)d_out;

  unsigned short* wsT = (unsigned short*)d_ws;           // 6 * [o][c] tiles (k3)
  unsigned short* wsF = wsT + 6 * (CDIM * CDIM);         // 6 * frag blobs (k1)
  unsigned short* a_t = wsF + 6 * (CDIM * CDIM);         // [C][N*N] bf16
  unsigned short* b_t = a_t + (size_t)CDIM * RDIM;
  unsigned short* k_t = b_t + (size_t)CDIM * RDIM;

  k0_prep<<<6, 256, 0, stream>>>(Wga, Wa, Wgb, Wb, Wgo, Wo, wsT, wsF);
  k1_proj<<<RDIM / 128, 256, 0, stream>>>(z, mask, g_in, b_in, bga, ba, bgb, bb,
                                          bgo, wsF, a_t, b_t, out);
  k2_einsum<<<CDIM * 16, 256, 0, stream>>>(a_t, b_t, k_t);
  k3_final<<<RDIM / 128, 256, 0, stream>>>(k_t, wsT, g_o, b_o, bo, out);
}